// Round 6
// baseline (305.159 us; speedup 1.0000x reference)
//
#include <hip/hip_runtime.h>

// IDWT2D db4, periodized. Input x: [64][256][256][16] f32 (cA|cH|cV|cD x 4ch),
// output: [64][512][512][4] f32.
//
// R4b: separable two-pass. Block = 16 j-rows x 256 cols, 512 threads.
// Pass1 (y-filter): thread=(col, lo/hi half), 4-row register sliding window
// reading global (each input row read once/block), writes I[buf][r][p][lh][col].
// Pass2 (x-filter): thread = output column (dense stores), lane-pairs share
// LDS reads via broadcast. 2 j-rows per chunk, double-buffered LDS (64 KB),
// ONE sync per chunk. Global prefetch issued a full chunk ahead.
// XCD-bijective block swizzle: 8 whole batches per XCD for halo L2 reuse.
// (R5 fix: nontemporal stores via native ext_vector float4.)

#define N 256
#define RJ 16
#define NC (RJ / 2)

typedef float nfloat4 __attribute__((ext_vector_type(4)));

__device__ __forceinline__ void fma4(float4& d, float s, const float4 a) {
  d.x = fmaf(s, a.x, d.x);
  d.y = fmaf(s, a.y, d.y);
  d.z = fmaf(s, a.z, d.z);
  d.w = fmaf(s, a.w, d.w);
}

__device__ __forceinline__ void nt_store4(const float4 v, float4* p) {
  nfloat4 nv;
  nv.x = v.x;
  nv.y = v.y;
  nv.z = v.z;
  nv.w = v.w;
  __builtin_nontemporal_store(nv, reinterpret_cast<nfloat4*>(p));
}

__global__ __launch_bounds__(512, 4) void idwt2_sep4_kernel(
    const float* __restrict__ x, float* __restrict__ out) {
  constexpr float LO[8] = {
      0.23037781330885523f,  0.7148465705525415f,  0.6308807679295904f,
      -0.02798376941698385f, -0.18703481171888114f, 0.030841381835986965f,
      0.032883011666982945f, -0.010597401784997278f};
  constexpr float HIW[8] = {
      -0.010597401784997278f, -0.032883011666982945f, 0.030841381835986965f,
      0.18703481171888114f,  -0.02798376941698385f,  -0.6308807679295904f,
      0.7148465705525415f,   -0.23037781330885523f};
  const float Lw[2][4] = {{LO[6], LO[4], LO[2], LO[0]},
                          {LO[7], LO[5], LO[3], LO[1]}};
  const float Hw[2][4] = {{HIW[6], HIW[4], HIW[2], HIW[0]},
                          {HIW[7], HIW[5], HIW[3], HIW[1]}};

  // [buf][row-in-chunk][p][lo/hi][col] float4 = 64 KB
  __shared__ float4 I[2][2][2][2][N];

  const int t = threadIdx.x;
  const int bx = blockIdx.x;
  // Bijective swizzle (grid 1024): XCD(orig) = orig>>7 -> 8 batches/XCD.
  const int orig = ((bx & 7) << 7) | (bx >> 3);
  const int b = orig >> 4;
  const int r0 = (orig & 15) * RJ;

  const float4* xb = reinterpret_cast<const float4*>(x) + (size_t)b * N * N * 4;
  float4* ob = reinterpret_cast<float4*>(out) + (size_t)b * (2 * N) * (2 * N);

  // ---- Pass1 identity: column + lo/hi half ----
  const int tcol = t & (N - 1);
  const int thalf = t >> 8;  // 0: lo from (cA,cH); 1: hi from (cV,cD)
  const float4* xcolp = xb + (size_t)tcol * 4 + thalf * 2;

  float4 wA[4], wB[4], nA0, nB0, nA1, nB1;
  auto ldrow = [&](int lr, float4& A, float4& B) {
    const int gr = (r0 + lr) & (N - 1);
    A = xcolp[(size_t)gr * (N * 4)];
    B = xcolp[(size_t)gr * (N * 4) + 1];
  };

#pragma unroll
  for (int m = 0; m < 4; ++m) ldrow(m, wA[m], wB[m]);
  ldrow(4, nA0, nB0);
  ldrow(5, nA1, nB1);

  // y-filter local j-row j into I[buf][r]; window slot (j+sy)&3 = row j+sy.
  auto p1 = [&](int j, int buf, int r) {
    float4 v0 = make_float4(0.f, 0.f, 0.f, 0.f);
    float4 v1 = make_float4(0.f, 0.f, 0.f, 0.f);
#pragma unroll
    for (int sy = 0; sy < 4; ++sy) {
      const float4 a = wA[(j + sy) & 3];
      const float4 bb = wB[(j + sy) & 3];
      fma4(v0, Lw[0][sy], a);
      fma4(v0, Hw[0][sy], bb);
      fma4(v1, Lw[1][sy], a);
      fma4(v1, Hw[1][sy], bb);
    }
    I[buf][r][0][thalf][tcol] = v0;
    I[buf][r][1][thalf][tcol] = v1;
  };

  // Prologue: chunk 0 into buf 0; prefetch rows 6,7.
  p1(0, 0, 0);
  wA[0] = nA0;
  wB[0] = nB0;
  p1(1, 0, 1);
  wA[1] = nA1;
  wB[1] = nB1;
  ldrow(6, nA0, nB0);
  ldrow(7, nA1, nB1);
  __syncthreads();

  // ---- Pass2 identity: output column t (dense stores) ----
  const int jx = t >> 1;
  const int q = t & 1;
  float Lq[4], Hq[4];
#pragma unroll
  for (int s = 0; s < 4; ++s) {
    Lq[s] = q ? Lw[1][s] : Lw[0][s];
    Hq[s] = q ? Hw[1][s] : Hw[0][s];
  }

#pragma unroll 2
  for (int c = 0; c < NC; ++c) {
    const int buf = c & 1;

    // ---- Pass2: x-filter chunk c (j-rows 2c, 2c+1) ----
#pragma unroll
    for (int r = 0; r < 2; ++r) {
      float4 o0 = make_float4(0.f, 0.f, 0.f, 0.f);
      float4 o1 = make_float4(0.f, 0.f, 0.f, 0.f);
#pragma unroll
      for (int s = 0; s < 4; ++s) {
        const int xc = (jx + s) & (N - 1);
        fma4(o0, Lq[s], I[buf][r][0][0][xc]);
        fma4(o0, Hq[s], I[buf][r][0][1][xc]);
        fma4(o1, Lq[s], I[buf][r][1][0][xc]);
        fma4(o1, Hq[s], I[buf][r][1][1][xc]);
      }
      const int jy = r0 + 2 * c + r;
      float4* po = ob + (size_t)(2 * jy) * (2 * N) + t;
      nt_store4(o0, po);
      nt_store4(o1, po + 2 * N);
    }

    if (c < NC - 1) {
      // ---- Pass1: chunk c+1 (rows 2c+2, 2c+3) into other buffer ----
      p1(2 * c + 2, buf ^ 1, 0);
      wA[(2 * c + 2) & 3] = nA0;
      wB[(2 * c + 2) & 3] = nB0;
      p1(2 * c + 3, buf ^ 1, 1);
      wA[(2 * c + 3) & 3] = nA1;
      wB[(2 * c + 3) & 3] = nB1;

      // ---- Prefetch window rows for chunk c+2 (consumed next iter) ----
      if (c < NC - 2) {
        ldrow(2 * c + 8, nA0, nB0);
        if (2 * c + 9 <= RJ + 2) ldrow(2 * c + 9, nA1, nB1);
      }
      __syncthreads();
    }
  }
}

extern "C" void kernel_launch(void* const* d_in, const int* in_sizes, int n_in,
                              void* d_out, int out_size, void* d_ws,
                              size_t ws_size, hipStream_t stream) {
  const float* x = reinterpret_cast<const float*>(d_in[0]);
  float* out = reinterpret_cast<float*>(d_out);
  const int grid = 64 * (N / RJ);  // 1024 blocks
  idwt2_sep4_kernel<<<grid, 512, 0, stream>>>(x, out);
}

// Round 7
// 117.412 us; speedup vs baseline: 2.5991x; 2.5991x over previous
//
#include <hip/hip_runtime.h>

// IDWT2D db4, periodized. Input x: [64][256][256][16] f32 (cA|cH|cV|cD x 4ch),
// output: [64][512][512][4] f32.
//
// R6: R4b structure, minus nontemporal stores (they doubled WRITE_SIZE via
// sub-line HBM writes) and minus the XCD swizzle (undefined blockIdx->XCD
// mapping scrambled halo locality; FETCH tripled). Natural block order:
// consecutive blocks = adjacent row-groups of the same batch.
// Block = 16 j-rows x 256 cols, 512 threads, VGPR ~64 (2 blocks/CU).
// Pass1: y-filter, 4-row register window, global reads (each row once/block).
// Pass2: x-filter, thread = output column (dense coalesced f4 stores).
// 2 j-rows/chunk, double-buffered 64 KB LDS, 1 sync/chunk, prefetch 1 chunk
// ahead.

#define N 256
#define RJ 16
#define NC (RJ / 2)

__device__ __forceinline__ void fma4(float4& d, float s, const float4 a) {
  d.x = fmaf(s, a.x, d.x);
  d.y = fmaf(s, a.y, d.y);
  d.z = fmaf(s, a.z, d.z);
  d.w = fmaf(s, a.w, d.w);
}

__global__ __launch_bounds__(512, 4) void idwt2_sep6_kernel(
    const float* __restrict__ x, float* __restrict__ out) {
  constexpr float LO[8] = {
      0.23037781330885523f,  0.7148465705525415f,  0.6308807679295904f,
      -0.02798376941698385f, -0.18703481171888114f, 0.030841381835986965f,
      0.032883011666982945f, -0.010597401784997278f};
  constexpr float HIW[8] = {
      -0.010597401784997278f, -0.032883011666982945f, 0.030841381835986965f,
      0.18703481171888114f,  -0.02798376941698385f,  -0.6308807679295904f,
      0.7148465705525415f,   -0.23037781330885523f};
  const float Lw[2][4] = {{LO[6], LO[4], LO[2], LO[0]},
                          {LO[7], LO[5], LO[3], LO[1]}};
  const float Hw[2][4] = {{HIW[6], HIW[4], HIW[2], HIW[0]},
                          {HIW[7], HIW[5], HIW[3], HIW[1]}};

  // [buf][row-in-chunk][p][lo/hi][col] float4 = 64 KB
  __shared__ float4 I[2][2][2][2][N];

  const int t = threadIdx.x;
  const int bx = blockIdx.x;
  const int b = bx >> 4;           // batch: 16 consecutive blocks per batch
  const int r0 = (bx & 15) * RJ;   // row-group within batch

  const float4* xb = reinterpret_cast<const float4*>(x) + (size_t)b * N * N * 4;
  float4* ob = reinterpret_cast<float4*>(out) + (size_t)b * (2 * N) * (2 * N);

  // ---- Pass1 identity: column + lo/hi half ----
  const int tcol = t & (N - 1);
  const int thalf = t >> 8;  // 0: lo from (cA,cH); 1: hi from (cV,cD)
  const float4* xcolp = xb + (size_t)tcol * 4 + thalf * 2;

  float4 wA[4], wB[4], nA0, nB0, nA1, nB1;
  auto ldrow = [&](int lr, float4& A, float4& B) {
    const int gr = (r0 + lr) & (N - 1);
    A = xcolp[(size_t)gr * (N * 4)];
    B = xcolp[(size_t)gr * (N * 4) + 1];
  };

#pragma unroll
  for (int m = 0; m < 4; ++m) ldrow(m, wA[m], wB[m]);
  ldrow(4, nA0, nB0);
  ldrow(5, nA1, nB1);

  // y-filter local j-row j into I[buf][r]; window slot (j+sy)&3 = row j+sy.
  auto p1 = [&](int j, int buf, int r) {
    float4 v0 = make_float4(0.f, 0.f, 0.f, 0.f);
    float4 v1 = make_float4(0.f, 0.f, 0.f, 0.f);
#pragma unroll
    for (int sy = 0; sy < 4; ++sy) {
      const float4 a = wA[(j + sy) & 3];
      const float4 bb = wB[(j + sy) & 3];
      fma4(v0, Lw[0][sy], a);
      fma4(v0, Hw[0][sy], bb);
      fma4(v1, Lw[1][sy], a);
      fma4(v1, Hw[1][sy], bb);
    }
    I[buf][r][0][thalf][tcol] = v0;
    I[buf][r][1][thalf][tcol] = v1;
  };

  // Prologue: chunk 0 into buf 0; prefetch rows 6,7.
  p1(0, 0, 0);
  wA[0] = nA0;
  wB[0] = nB0;
  p1(1, 0, 1);
  wA[1] = nA1;
  wB[1] = nB1;
  ldrow(6, nA0, nB0);
  ldrow(7, nA1, nB1);
  __syncthreads();

  // ---- Pass2 identity: output column t (dense stores) ----
  const int jx = t >> 1;
  const int q = t & 1;
  float Lq[4], Hq[4];
#pragma unroll
  for (int s = 0; s < 4; ++s) {
    Lq[s] = q ? Lw[1][s] : Lw[0][s];
    Hq[s] = q ? Hw[1][s] : Hw[0][s];
  }

#pragma unroll 2
  for (int c = 0; c < NC; ++c) {
    const int buf = c & 1;

    // ---- Pass2: x-filter chunk c (j-rows 2c, 2c+1) ----
#pragma unroll
    for (int r = 0; r < 2; ++r) {
      float4 o0 = make_float4(0.f, 0.f, 0.f, 0.f);
      float4 o1 = make_float4(0.f, 0.f, 0.f, 0.f);
#pragma unroll
      for (int s = 0; s < 4; ++s) {
        const int xc = (jx + s) & (N - 1);
        fma4(o0, Lq[s], I[buf][r][0][0][xc]);
        fma4(o0, Hq[s], I[buf][r][0][1][xc]);
        fma4(o1, Lq[s], I[buf][r][1][0][xc]);
        fma4(o1, Hq[s], I[buf][r][1][1][xc]);
      }
      const int jy = r0 + 2 * c + r;
      float4* po = ob + (size_t)(2 * jy) * (2 * N) + t;
      po[0] = o0;
      po[2 * N] = o1;
    }

    if (c < NC - 1) {
      // ---- Pass1: chunk c+1 (rows 2c+2, 2c+3) into other buffer ----
      p1(2 * c + 2, buf ^ 1, 0);
      wA[(2 * c + 2) & 3] = nA0;
      wB[(2 * c + 2) & 3] = nB0;
      p1(2 * c + 3, buf ^ 1, 1);
      wA[(2 * c + 3) & 3] = nA1;
      wB[(2 * c + 3) & 3] = nB1;

      // ---- Prefetch window rows for chunk c+2 (consumed next iter) ----
      if (c < NC - 2) {
        ldrow(2 * c + 8, nA0, nB0);
        if (2 * c + 9 <= RJ + 2) ldrow(2 * c + 9, nA1, nB1);
      }
      __syncthreads();
    }
  }
}

extern "C" void kernel_launch(void* const* d_in, const int* in_sizes, int n_in,
                              void* d_out, int out_size, void* d_ws,
                              size_t ws_size, hipStream_t stream) {
  const float* x = reinterpret_cast<const float*>(d_in[0]);
  float* out = reinterpret_cast<float*>(d_out);
  const int grid = 64 * (N / RJ);  // 1024 blocks
  idwt2_sep6_kernel<<<grid, 512, 0, stream>>>(x, out);
}